// Round 9
// baseline (759.767 us; speedup 1.0000x reference)
//
#include <hip/hip_runtime.h>
#include <hip/hip_cooperative_groups.h>

namespace cg = cooperative_groups;

#define N_NODES 100000
#define N_EDGESC 800000
#define HID 128
#define NGRAPH 128
#define BN_EPS 1e-5f
#define NREP 32    // BN-stats atomic replicas
#define PS 136     // LDS row stride in shorts: 272B = 16B-aligned, <=2-way banks
#define MLP_BLOCKS ((N_NODES + 63) / 64)   // 1563 tiles, one per block

// ---- atomic-free edge partition parameters ----
#define PBLK 256                     // partition blocks
#define PCHUNK 3125                  // edges per partition block (256*3125 = 800000 exact)
#define NCOARSE 196                  // 512-node coarse buckets: bin = dst>>9 (196*512 >= 100000)
#define HISTN (NCOARSE * PBLK)       // 50176
#define HSCAN_BLOCKS (HISTN / 1024)  // 49 exact
#define CVT_BLOCKS 12500             // 3200000 float4 / 256

typedef __bf16 bf16x8 __attribute__((ext_vector_type(8)));
typedef float f32x4 __attribute__((ext_vector_type(4)));

__device__ inline unsigned short f2bf(float f) {     // RNE fp32 -> bf16
    unsigned int u = __float_as_uint(f);
    unsigned int r = u + 0x7FFFu + ((u >> 16) & 1u);
    return (unsigned short)(r >> 16);
}
__device__ inline float b2f(unsigned short u) {
    return __uint_as_float(((unsigned int)u) << 16);
}

// ================= cooperative partition mega-kernel =================
// JOURNAL: LDS *int* atomics native & cheap; LDS *float* atomicAdd = CAS
// loop disaster (round-1). Round-6: don't fuse gather into MLP. Round-7:
// degree-sort perm regressed (locality loss). Round-8 bookkeeping: each
// launch+gap ~3-4us -> merge the 5 partition launches into 1 cooperative
// kernel with grid.sync() (256 blocks x 256 thr, trivially co-resident).
__global__ __launch_bounds__(256) void k_prep(
    const int* __restrict__ src, const int* __restrict__ dst,
    const int* __restrict__ batch,
    int* __restrict__ hist, int* __restrict__ bsum, int* __restrict__ gstart,
    unsigned int* __restrict__ pk1, int* __restrict__ eidx, int* __restrict__ off)
{
    cg::grid_group grid = cg::this_grid();
    __shared__ int S[1280];   // carved per phase (max: psort 512+512+256)
    const int tid = threadIdx.x;
    const int b = blockIdx.x;

    // ---- phase 1: per-block coarse histogram (transposed store) ----
    {
        int* h = S;   // 196
        if (tid < NCOARSE) h[tid] = 0;
        __syncthreads();
        int base = b * PCHUNK;
        for (int i = tid; i < PCHUNK; i += 256)
            atomicAdd(&h[dst[base + i] >> 9], 1);
        __syncthreads();
        if (tid < NCOARSE) hist[tid * PBLK + b] = h[tid];
    }
    grid.sync();

    // ---- phase 2: block-level exclusive scans (blocks 0..48; 49*1024 exact) ----
    if (b < HSCAN_BLOCKS) {
        int* ts = S;   // 256
        int base = b * 1024 + tid * 4;
        int v[4], s = 0;
        #pragma unroll
        for (int i = 0; i < 4; ++i) { v[i] = hist[base + i]; s += v[i]; }
        ts[tid] = s;
        __syncthreads();
        for (int d = 1; d < 256; d <<= 1) {
            int t = (tid >= d) ? ts[tid - d] : 0;
            __syncthreads();
            ts[tid] += t;
            __syncthreads();
        }
        int run = ts[tid] - s;
        #pragma unroll
        for (int i = 0; i < 4; ++i) { hist[base + i] = run; run += v[i]; }
        if (tid == 255) bsum[b] = ts[255];
    }
    grid.sync();

    // ---- phase 3: top-level scan (lane 0) + per-graph bounds (128 lanes) ----
    if (b == 0) {
        if (tid == 0) {
            int run = 0;
            for (int i = 0; i < HSCAN_BLOCKS; ++i) { int t = bsum[i]; bsum[i] = run; run += t; }
        }
        if (tid < 128) {
            int g = tid;
            int lo = 0, hi = N_NODES;
            while (lo < hi) {
                int mid = (lo + hi) >> 1;
                if (batch[mid] < g) lo = mid + 1; else hi = mid;
            }
            gstart[g] = lo;
            if (g == 0) gstart[NGRAPH] = N_NODES;
        }
    }
    grid.sync();

    // ---- phase 4: scatter into coarse buckets (bsum added inline) ----
    {
        int* cur = S;   // 196
        if (tid < NCOARSE) {
            int idx = tid * PBLK + b;
            cur[tid] = hist[idx] + bsum[idx >> 10];
        }
        __syncthreads();
        int base = b * PCHUNK;
        for (int i = tid; i < PCHUNK; i += 256) {
            int sv = src[base + i], d = dst[base + i];
            int p = atomicAdd(&cur[d >> 9], 1);
            pk1[p] = ((unsigned int)sv << 9) | (unsigned int)(d & 511);
        }
    }
    grid.sync();

    // ---- phase 5: per-node counting sort -> CSR (blocks 0..195) ----
    if (b < NCOARSE) {
        int* h = S; int* cur = S + 512; int* ts = S + 1024;
        const int i0 = b * PBLK;
        const int e0 = hist[i0] + bsum[i0 >> 10];
        int e1 = N_EDGESC;
        if (b < NCOARSE - 1) {
            const int i1 = (b + 1) * PBLK;
            e1 = hist[i1] + bsum[i1 >> 10];
        }
        const int cnt = e1 - e0;
        h[tid] = 0; h[tid + 256] = 0;
        __syncthreads();
        for (int i = tid; i < cnt; i += 256)
            atomicAdd(&h[pk1[e0 + i] & 511], 1);
        __syncthreads();
        int v0 = h[tid * 2], v1 = h[tid * 2 + 1];
        int s = v0 + v1;
        ts[tid] = s;
        __syncthreads();
        for (int d = 1; d < 256; d <<= 1) {
            int t = (tid >= d) ? ts[tid - d] : 0;
            __syncthreads();
            ts[tid] += t;
            __syncthreads();
        }
        int run = e0 + ts[tid] - s;
        int n0 = b * 512 + tid * 2;
        cur[tid * 2]     = run;
        cur[tid * 2 + 1] = run + v0;
        if (n0     <= N_NODES) off[n0]     = run;
        if (n0 + 1 <= N_NODES) off[n0 + 1] = run + v0;
        __syncthreads();
        for (int i = tid; i < cnt; i += 256) {
            unsigned int u = pk1[e0 + i];
            int p = atomicAdd(&cur[u & 511], 1);
            eidx[p] = (int)(u >> 9);
        }
    }
}

// ================ dtype conversion (merged x-cvt + weight-cvt) ================
__global__ __launch_bounds__(256) void k_cvtw(const float* __restrict__ X,
    unsigned short* __restrict__ Y,
    const float* __restrict__ Wa, const float* __restrict__ Wb,
    const float* __restrict__ Wc, const float* __restrict__ Wd,
    unsigned short* __restrict__ WT)
{
    int blk = blockIdx.x;
    if (blk < CVT_BLOCKS) {
        int i = blk * 256 + threadIdx.x;
        float4 v = ((const float4*)X)[i];
        ((ushort4*)Y)[i] = make_ushort4(f2bf(v.x), f2bf(v.y), f2bf(v.z), f2bf(v.w));
    } else {
        int idx = (blk - CVT_BLOCKS) * 256 + threadIdx.x;   // 0..65535
        int mat = idx >> 14, w = idx & 16383;
        int k = w >> 7, n = w & 127;
        const float* W = (mat == 0) ? Wa : (mat == 1) ? Wb : (mat == 2) ? Wc : Wd;
        WT[mat * 16384 + n * 128 + k] = f2bf(W[w]);
    }
}

// ================ gather: OUT[n] = f(X[n]) + sum f(X[j]) ================
// (proven round-0/5 structure: sequential node order, register accumulation,
//  16 lanes/node, 8-way edge ILP — do not touch)
template<bool BN>
__device__ inline void acc_row(float* acc, uint4 v,
                               const float* sc, const float* sh)
{
    unsigned int u[4] = {v.x, v.y, v.z, v.w};
    #pragma unroll
    for (int j = 0; j < 4; ++j) {
        float lo = b2f((unsigned short)u[j]);
        float hi = b2f((unsigned short)(u[j] >> 16));
        if (BN) {
            lo = fmaxf(lo * sc[2*j]   + sh[2*j],   0.f);
            hi = fmaxf(hi * sc[2*j+1] + sh[2*j+1], 0.f);
        }
        acc[2*j]   += lo;
        acc[2*j+1] += hi;
    }
}

template<bool BN>
__global__ __launch_bounds__(256) void k_gather(
    const unsigned short* __restrict__ X, const float* __restrict__ SC,
    const int* __restrict__ off, const int* __restrict__ eidx,
    unsigned short* __restrict__ OUT, int M)
{
    int n = blockIdx.x * 16 + (threadIdx.x >> 4);
    if (n >= M) return;
    const int lane = threadIdx.x & 15;
    const size_t co = (size_t)lane * 8;

    float sc[8], sh[8];
    if (BN) {
        *(float4*)&sc[0] = ((const float4*)SC)[lane * 2];
        *(float4*)&sc[4] = ((const float4*)SC)[lane * 2 + 1];
        *(float4*)&sh[0] = ((const float4*)SC)[32 + lane * 2];
        *(float4*)&sh[4] = ((const float4*)SC)[32 + lane * 2 + 1];
    }

    float acc[8] = {0.f, 0.f, 0.f, 0.f, 0.f, 0.f, 0.f, 0.f};
    acc_row<BN>(acc, *(const uint4*)(X + (size_t)n * HID + co), sc, sh);

    int k = off[n], kend = off[n + 1];
    for (; k + 7 < kend; k += 8) {       // 8-way ILP: 128B in flight per lane
        uint4 v0 = *(const uint4*)(X + (size_t)eidx[k]   * HID + co);
        uint4 v1 = *(const uint4*)(X + (size_t)eidx[k+1] * HID + co);
        uint4 v2 = *(const uint4*)(X + (size_t)eidx[k+2] * HID + co);
        uint4 v3 = *(const uint4*)(X + (size_t)eidx[k+3] * HID + co);
        uint4 v4 = *(const uint4*)(X + (size_t)eidx[k+4] * HID + co);
        uint4 v5 = *(const uint4*)(X + (size_t)eidx[k+5] * HID + co);
        uint4 v6 = *(const uint4*)(X + (size_t)eidx[k+6] * HID + co);
        uint4 v7 = *(const uint4*)(X + (size_t)eidx[k+7] * HID + co);
        acc_row<BN>(acc, v0, sc, sh); acc_row<BN>(acc, v1, sc, sh);
        acc_row<BN>(acc, v2, sc, sh); acc_row<BN>(acc, v3, sc, sh);
        acc_row<BN>(acc, v4, sc, sh); acc_row<BN>(acc, v5, sc, sh);
        acc_row<BN>(acc, v6, sc, sh); acc_row<BN>(acc, v7, sc, sh);
    }
    for (; k + 3 < kend; k += 4) {
        uint4 v0 = *(const uint4*)(X + (size_t)eidx[k]   * HID + co);
        uint4 v1 = *(const uint4*)(X + (size_t)eidx[k+1] * HID + co);
        uint4 v2 = *(const uint4*)(X + (size_t)eidx[k+2] * HID + co);
        uint4 v3 = *(const uint4*)(X + (size_t)eidx[k+3] * HID + co);
        acc_row<BN>(acc, v0, sc, sh); acc_row<BN>(acc, v1, sc, sh);
        acc_row<BN>(acc, v2, sc, sh); acc_row<BN>(acc, v3, sc, sh);
    }
    for (; k < kend; ++k) {
        uint4 v = *(const uint4*)(X + (size_t)eidx[k] * HID + co);
        acc_row<BN>(acc, v, sc, sh);
    }

    uint4 o;
    o.x = (unsigned int)f2bf(acc[0]) | ((unsigned int)f2bf(acc[1]) << 16);
    o.y = (unsigned int)f2bf(acc[2]) | ((unsigned int)f2bf(acc[3]) << 16);
    o.z = (unsigned int)f2bf(acc[4]) | ((unsigned int)f2bf(acc[5]) << 16);
    o.w = (unsigned int)f2bf(acc[6]) | ((unsigned int)f2bf(acc[7]) << 16);
    *(uint4*)(OUT + (size_t)n * HID + co) = o;
}

// ============== fused MLP + last-block BN finalize ==============
// (proven round-5 body; round-8 addition: the last block to finish computes
//  SC from Srep in-kernel. Cross-XCD safety: reads via atomicAdd(p,0.f)
//  coherent RMW; counter self-resets for graph replay.)
__global__ __launch_bounds__(256) void k_mlp(
    const unsigned short* __restrict__ A,
    const unsigned short* __restrict__ WTa, const float* __restrict__ ba,
    const unsigned short* __restrict__ WTb, const float* __restrict__ bb,
    unsigned short* __restrict__ Cb, float* __restrict__ Srep,
    const float* __restrict__ gamma, const float* __restrict__ beta,
    float* __restrict__ SCout, int* __restrict__ done, int M)
{
    __shared__ unsigned short Abuf[64 * PS];   // A tile, then C staging
    __shared__ unsigned short Hbuf[64 * PS];   // hidden exchange

    const int tid  = threadIdx.x;
    const int wave = tid >> 6;     // 0..3: owns cols [wave*32, wave*32+32)
    const int lane = tid & 63;
    const int m    = lane & 15;
    const int quad = lane >> 4;
    const int rowbase = blockIdx.x * 64;

    // ---- weight fragments -> registers (once per block) ----
    bf16x8 WA[2][4], WB[2][4];
    float bav[2], bbv[2];
    #pragma unroll
    for (int n0 = 0; n0 < 2; ++n0) {
        const int col = (wave * 2 + n0) * 16 + m;
        const size_t cb = (size_t)col * HID + quad * 8;
        #pragma unroll
        for (int kk = 0; kk < 4; ++kk) {
            WA[n0][kk] = *(const bf16x8*)(WTa + cb + kk * 32);
            WB[n0][kk] = *(const bf16x8*)(WTb + cb + kk * 32);
        }
        bav[n0] = ba[col];
        bbv[n0] = bb[col];
    }

    // ---- stage A tile (64x128 bf16 = 1024 uint4; 4 per thread) ----
    // NOTE: last tile overreads <=31 rows past A's end -> lands in Yb (valid).
    {
        const uint4* Ag = (const uint4*)(A + (size_t)rowbase * HID);
        #pragma unroll
        for (int i = 0; i < 4; ++i) {
            int u = tid + i * 256;
            uint4 v = Ag[u];
            int r = u >> 4, c = u & 15;
            *(uint4*)(Abuf + r * PS + c * 8) = v;
        }
    }
    __syncthreads();

    // ---- GEMM-a ----
    f32x4 acc[4][2];
    #pragma unroll
    for (int rg = 0; rg < 4; ++rg)
        #pragma unroll
        for (int n0 = 0; n0 < 2; ++n0) acc[rg][n0] = {0.f, 0.f, 0.f, 0.f};
    #pragma unroll
    for (int rg = 0; rg < 4; ++rg) {
        #pragma unroll
        for (int kk = 0; kk < 4; ++kk) {
            bf16x8 af = *(const bf16x8*)(Abuf + (rg*16 + m) * PS + quad*8 + kk*32);
            acc[rg][0] = __builtin_amdgcn_mfma_f32_16x16x32_bf16(af, WA[0][kk], acc[rg][0], 0, 0, 0);
            acc[rg][1] = __builtin_amdgcn_mfma_f32_16x16x32_bf16(af, WA[1][kk], acc[rg][1], 0, 0, 0);
        }
    }

    // H = relu(acc + ba) -> Hbuf
    #pragma unroll
    for (int rg = 0; rg < 4; ++rg)
        #pragma unroll
        for (int n0 = 0; n0 < 2; ++n0)
            #pragma unroll
            for (int i = 0; i < 4; ++i)
                Hbuf[(rg*16 + quad*4 + i) * PS + (wave*2 + n0)*16 + m] =
                    f2bf(fmaxf(acc[rg][n0][i] + bav[n0], 0.f));
    __syncthreads();

    // ---- GEMM-b ----
    #pragma unroll
    for (int rg = 0; rg < 4; ++rg)
        #pragma unroll
        for (int n0 = 0; n0 < 2; ++n0) acc[rg][n0] = {0.f, 0.f, 0.f, 0.f};
    #pragma unroll
    for (int rg = 0; rg < 4; ++rg) {
        #pragma unroll
        for (int kk = 0; kk < 4; ++kk) {
            bf16x8 hf = *(const bf16x8*)(Hbuf + (rg*16 + m) * PS + quad*8 + kk*32);
            acc[rg][0] = __builtin_amdgcn_mfma_f32_16x16x32_bf16(hf, WB[0][kk], acc[rg][0], 0, 0, 0);
            acc[rg][1] = __builtin_amdgcn_mfma_f32_16x16x32_bf16(hf, WB[1][kk], acc[rg][1], 0, 0, 0);
        }
    }

    // ---- epilogue: bias, BN stats, C-stage into Abuf ----
    const bool full = (rowbase + 64 <= M);
    float s[2] = {0.f, 0.f}, s2[2] = {0.f, 0.f};
    #pragma unroll
    for (int rg = 0; rg < 4; ++rg) {
        #pragma unroll
        for (int n0 = 0; n0 < 2; ++n0) {
            #pragma unroll
            for (int i = 0; i < 4; ++i) {
                float v = acc[rg][n0][i] + bbv[n0];
                if (full || rowbase + rg*16 + quad*4 + i < M) { s[n0] += v; s2[n0] += v*v; }
                Abuf[(rg*16 + quad*4 + i) * PS + (wave*2 + n0)*16 + m] = f2bf(v);
            }
        }
    }
    __syncthreads();

    // ---- coalesced C store (1024 uint4; 4 per thread) ----
    #pragma unroll
    for (int i = 0; i < 4; ++i) {
        int u = tid + i * 256;
        int r = u >> 4, c = u & 15;
        uint4 v = *(const uint4*)(Abuf + r * PS + c * 8);
        int g = rowbase + r;
        if (g < M) *(uint4*)(Cb + (size_t)g * HID + c * 8) = v;
    }

    // ---- BN stats: reduce over quads, atomics into replicas ----
    #pragma unroll
    for (int n0 = 0; n0 < 2; ++n0) {
        s[n0]  += __shfl_xor(s[n0], 16, 64);
        s[n0]  += __shfl_xor(s[n0], 32, 64);
        s2[n0] += __shfl_xor(s2[n0], 16, 64);
        s2[n0] += __shfl_xor(s2[n0], 32, 64);
    }
    if (quad == 0) {
        float* R = Srep + (size_t)((blockIdx.x * 4 + wave) & (NREP - 1)) * 256;
        #pragma unroll
        for (int n0 = 0; n0 < 2; ++n0) {
            int col = (wave * 2 + n0) * 16 + m;
            atomicAdd(&R[col], s[n0]);
            atomicAdd(&R[128 + col], s2[n0]);
        }
    }

    // ---- last block finalizes BN scale/shift ----
    __threadfence();
    __shared__ int isLast;
    if (tid == 0) isLast = (atomicAdd(done, 1) == (int)gridDim.x - 1) ? 1 : 0;
    __syncthreads();
    if (isLast) {
        if (tid < 128) {
            int f = tid;
            float ss = 0.f, ss2 = 0.f;
            for (int r = 0; r < NREP; ++r) {
                ss  += atomicAdd(&Srep[r * 256 + f], 0.f);        // coherent read
                ss2 += atomicAdd(&Srep[r * 256 + 128 + f], 0.f);
            }
            float mean = ss / (float)M;
            float var = fmaxf(ss2 / (float)M - mean * mean, 0.f);
            float scv = gamma[f] * rsqrtf(var + BN_EPS);
            SCout[f] = scv;
            SCout[HID + f] = beta[f] - mean * scv;
        }
        __syncthreads();
        if (tid == 0) *done = 0;   // reset for graph replay
    }
}

// ---------------- fused pooling (BN+ReLU) + classifier head ----------------
// One 512-thread block per graph: pool into LDS, sync, head on wave 0.
// Removes P buffer + its memset + the separate k_head launch.
__global__ __launch_bounds__(512) void k_poolhead(
    const unsigned short* __restrict__ H, const float* __restrict__ SC,
    const int* __restrict__ gstart, const float* __restrict__ Wlin,
    const float* __restrict__ blin, float* __restrict__ out)
{
    __shared__ float ls[512];
    __shared__ float pooled[128];
    int g = blockIdx.x;
    int beg = gstart[g], end = gstart[g + 1];
    int f = threadIdx.x & 127, q = threadIdx.x >> 7;   // q in 0..3
    float scv = SC[f], shv = SC[HID + f];
    float s = 0.f;
    for (int r = beg + q; r < end; r += 4)
        s += fmaxf(b2f(H[(size_t)r * HID + f]) * scv + shv, 0.f);
    ls[threadIdx.x] = s;
    __syncthreads();
    if (threadIdx.x < 128)
        pooled[threadIdx.x] = ls[threadIdx.x] + ls[threadIdx.x + 128]
                            + ls[threadIdx.x + 256] + ls[threadIdx.x + 384];
    __syncthreads();
    if (threadIdx.x < 64) {
        int l = threadIdx.x;
        float inv = 1.f / (float)max(end - beg, 1);
        float p0 = pooled[l] * inv;
        float p1 = pooled[64 + l] * inv;
        float lg[10];
        #pragma unroll
        for (int c = 0; c < 10; ++c) {
            float v = p0 * Wlin[l * 10 + c] + p1 * Wlin[(64 + l) * 10 + c];
            #pragma unroll
            for (int o = 32; o > 0; o >>= 1) v += __shfl_down(v, o);
            lg[c] = v;
        }
        if (l == 0) {
            float mx = -1e30f;
            #pragma unroll
            for (int c = 0; c < 10; ++c) { lg[c] += blin[c]; mx = fmaxf(mx, lg[c]); }
            float se = 0.f;
            #pragma unroll
            for (int c = 0; c < 10; ++c) se += expf(lg[c] - mx);
            float lse = mx + logf(se);
            #pragma unroll
            for (int c = 0; c < 10; ++c) out[g * 10 + c] = lg[c] - lse;
        }
    }
}

extern "C" void kernel_launch(void* const* d_in, const int* in_sizes, int n_in,
                              void* d_out, int out_size, void* d_ws, size_t ws_size,
                              hipStream_t stream)
{
    const float* x    = (const float*)d_in[0];
    const int*   ei   = (const int*)d_in[1];
    const int*   batch= (const int*)d_in[2];
    const float* W1a  = (const float*)d_in[3];
    const float* b1a  = (const float*)d_in[4];
    const float* W1b  = (const float*)d_in[5];
    const float* b1b  = (const float*)d_in[6];
    const float* g1   = (const float*)d_in[7];
    const float* be1  = (const float*)d_in[8];
    const float* W2a  = (const float*)d_in[9];
    const float* b2a  = (const float*)d_in[10];
    const float* W2b  = (const float*)d_in[11];
    const float* b2b  = (const float*)d_in[12];
    const float* g2   = (const float*)d_in[13];
    const float* be2  = (const float*)d_in[14];
    const float* Wl   = (const float*)d_in[15];
    const float* bl   = (const float*)d_in[16];
    float* out = (float*)d_out;

    const int* src = ei;
    const int* dst = ei + N_EDGESC;

    const size_t NM = (size_t)N_NODES * HID;    // 12.8M
    char* wsb = (char*)d_ws;
    // Ab first: k_mlp overreads <=31 rows past Ab -> lands in Yb (valid).
    unsigned short* Ab  = (unsigned short*)wsb;                 // NM u16 (agg out)
    unsigned short* Yb  = Ab + NM;                              // NM u16 (Cb1)
    unsigned short* Xb  = Yb + NM;                              // NM u16 (x / Cb2)
    // Srep1|Srep2|done contiguous -> single memset
    float* Srep1 = (float*)(Xb + NM);                           // NREP*256
    float* Srep2 = Srep1 + NREP * 256;                          // NREP*256
    int* done    = (int*)(Srep2 + NREP * 256);                  // 2 counters
    float* SC1  = (float*)(done + 2);                           // 256
    float* SC2  = SC1 + 256;                                    // 256
    unsigned short* WT = (unsigned short*)(SC2 + 256);          // 4*16384 u16
    int* hist   = (int*)(WT + 4 * 16384);                       // HISTN
    int* eidx   = hist + HISTN;                                 // N_EDGESC
    int* off    = eidx + N_EDGESC;                              // N_NODES+1
    int* bsum   = off + N_NODES + 1;                            // 64
    int* gstart = bsum + 64;                                    // NGRAPH+1
    // pk1 aliases Xb: dead before k_cvtw writes Xb (launch order below).
    unsigned int* pk1 = (unsigned int*)Xb;                      // N_EDGESC

    dim3 blk(256);
    const int gatBlocks = (N_NODES + 15) / 16;         // 6250

    // single memset: Srep1+Srep2+done (contiguous)
    hipMemsetAsync(Srep1, 0, 2 * NREP * 256 * sizeof(float) + 2 * sizeof(int),
                   stream);

    // ---- cooperative partition mega-kernel (5 launches -> 1) ----
    void* prepArgs[] = {
        (void*)&src, (void*)&dst, (void*)&batch,
        (void*)&hist, (void*)&bsum, (void*)&gstart,
        (void*)&pk1, (void*)&eidx, (void*)&off };
    hipLaunchCooperativeKernel((void*)k_prep, dim3(PBLK), blk,
                               prepArgs, 0, stream);

    // ---- conversions (after k_prep: k_cvtw overwrites pk1's alias region) ----
    k_cvtw<<<CVT_BLOCKS + 256, blk, 0, stream>>>(x, Xb, W1a, W1b, W2a, W2b, WT);

    // ---- conv1 (BN finalize folded into k_mlp's last block) ----
    k_gather<false><<<gatBlocks, blk, 0, stream>>>(Xb, nullptr, off, eidx, Ab, N_NODES);
    k_mlp<<<MLP_BLOCKS, blk, 0, stream>>>(Ab, WT, b1a, WT + 16384, b1b, Yb,
                                          Srep1, g1, be1, SC1, done, N_NODES);

    // ---- conv2 (BN1+ReLU fused into gather) ----
    k_gather<true><<<gatBlocks, blk, 0, stream>>>(Yb, SC1, off, eidx, Ab, N_NODES);
    k_mlp<<<MLP_BLOCKS, blk, 0, stream>>>(Ab, WT + 2 * 16384, b2a, WT + 3 * 16384,
                                          b2b, Xb, Srep2, g2, be2, SC2, done + 1, N_NODES);

    // ---- fused pool (BN2+ReLU) + head ----
    k_poolhead<<<NGRAPH, 512, 0, stream>>>(Xb, SC2, gstart, Wl, bl, out);
}

// Round 10
// 346.997 us; speedup vs baseline: 2.1896x; 2.1896x over previous
//
#include <hip/hip_runtime.h>

#define N_NODES 100000
#define N_EDGESC 800000
#define HID 128
#define NGRAPH 128
#define BN_EPS 1e-5f
#define NREP 32    // BN-stats atomic replicas
#define PS 136     // LDS row stride in shorts: 272B = 16B-aligned, <=2-way banks
#define MLP_BLOCKS ((N_NODES + 63) / 64)   // 1563 tiles, one per block

// ---- atomic-free edge partition parameters ----
#define PBLK 256                     // partition blocks
#define PCHUNK 3125                  // edges per partition block (256*3125 = 800000 exact)
#define NCOARSE 196                  // 512-node coarse buckets: bin = dst>>9 (196*512 >= 100000)
#define HISTN (NCOARSE * PBLK)       // 50176
#define HSCAN_BLOCKS (HISTN / 1024)  // 49 exact
#define CVT_BLOCKS 12500             // 3200000 float4 / 256

typedef __bf16 bf16x8 __attribute__((ext_vector_type(8)));
typedef float f32x4 __attribute__((ext_vector_type(4)));

__device__ inline unsigned short f2bf(float f) {     // RNE fp32 -> bf16
    unsigned int u = __float_as_uint(f);
    unsigned int r = u + 0x7FFFu + ((u >> 16) & 1u);
    return (unsigned short)(r >> 16);
}
__device__ inline float b2f(unsigned short u) {
    return __uint_as_float(((unsigned int)u) << 16);
}

// ================= atomic-free bucket partition =================
// JOURNAL: LDS *int* atomics native & cheap; LDS *float* atomicAdd = CAS
// loop disaster (round-1). Round-6: don't fuse gather into MLP (occupancy).
// Round-7: degree-sort perm regressed (locality loss). Round-9: last-block
// BN-finalize with __threadfence() wrecked k_mlp 21->168us (device-scope
// fence per wave + regalloc collapse 200->60 VGPR); cooperative grid.sync
// mega-kernel also slower than 5 small launches. BOTH REVERTED — keep the
// round-8 structure; one structural experiment per round.

__global__ __launch_bounds__(256) void k_phist(const int* __restrict__ dst,
                                               int* __restrict__ hist)
{
    __shared__ int h[NCOARSE];
    if (threadIdx.x < NCOARSE) h[threadIdx.x] = 0;
    __syncthreads();
    int base = blockIdx.x * PCHUNK;
    for (int i = threadIdx.x; i < PCHUNK; i += 256)
        atomicAdd(&h[dst[base + i] >> 9], 1);
    __syncthreads();
    if (threadIdx.x < NCOARSE)
        hist[threadIdx.x * PBLK + blockIdx.x] = h[threadIdx.x];
}

// generic exclusive-scan (in-place), 1024 elements per block
__global__ __launch_bounds__(256) void k_scan_block(int* __restrict__ a,
    int* __restrict__ bsum, int n)
{
    __shared__ int ts[256];
    int base = blockIdx.x * 1024 + threadIdx.x * 4;
    int v[4], s = 0;
    #pragma unroll
    for (int i = 0; i < 4; ++i) {
        int idx = base + i;
        v[i] = (idx < n) ? a[idx] : 0;
        s += v[i];
    }
    ts[threadIdx.x] = s;
    __syncthreads();
    for (int d = 1; d < 256; d <<= 1) {
        int t = (threadIdx.x >= d) ? ts[threadIdx.x - d] : 0;
        __syncthreads();
        ts[threadIdx.x] += t;
        __syncthreads();
    }
    int run = ts[threadIdx.x] - s;
    #pragma unroll
    for (int i = 0; i < 4; ++i) {
        int idx = base + i;
        if (idx < n) a[idx] = run;
        run += v[i];
    }
    if (threadIdx.x == 255) bsum[blockIdx.x] = ts[255];
}

// merged: serial top-level scan (lane 0) + per-graph bounds (all 128 lanes)
__global__ void k_scan_top_bounds(int* __restrict__ bsum, int nb,
    const int* __restrict__ batch, int* __restrict__ gstart)
{
    if (threadIdx.x == 0) {
        int run = 0;
        for (int i = 0; i < nb; ++i) { int t = bsum[i]; bsum[i] = run; run += t; }
    }
    int g = threadIdx.x;   // 128
    int lo = 0, hi = N_NODES;
    while (lo < hi) {
        int mid = (lo + hi) >> 1;
        if (batch[mid] < g) lo = mid + 1; else hi = mid;
    }
    gstart[g] = lo;
    if (g == 0) gstart[NGRAPH] = N_NODES;
}

// P1b: scatter into coarse buckets. LDS int cursors; bsum added inline.
// pk = (src<<9)|(dst&511).
__global__ __launch_bounds__(256) void k_pscatter(const int* __restrict__ src,
    const int* __restrict__ dst, const int* __restrict__ hist,
    const int* __restrict__ bsum, unsigned int* __restrict__ pk1)
{
    __shared__ int cur[NCOARSE];
    if (threadIdx.x < NCOARSE) {
        int idx = threadIdx.x * PBLK + blockIdx.x;
        cur[threadIdx.x] = hist[idx] + bsum[idx >> 10];
    }
    __syncthreads();
    int base = blockIdx.x * PCHUNK;
    for (int i = threadIdx.x; i < PCHUNK; i += 256) {
        int s = src[base + i], d = dst[base + i];
        int p = atomicAdd(&cur[d >> 9], 1);
        pk1[p] = ((unsigned int)s << 9) | (unsigned int)(d & 511);
    }
}

// P2: per-node counting sort within each coarse bucket (~4096 edges).
// Emits CSR: eidx (sorted by dst node) + off[n]. LDS int atomics only.
__global__ __launch_bounds__(256) void k_psort(const unsigned int* __restrict__ pk1,
    const int* __restrict__ hist, const int* __restrict__ bsum,
    int* __restrict__ eidx, int* __restrict__ off)
{
    __shared__ int h[512], cur[512], ts[256];
    const int b = blockIdx.x;   // 196
    const int i0 = b * PBLK;
    const int e0 = hist[i0] + bsum[i0 >> 10];
    int e1 = N_EDGESC;
    if (b < NCOARSE - 1) {
        const int i1 = (b + 1) * PBLK;
        e1 = hist[i1] + bsum[i1 >> 10];
    }
    const int cnt = e1 - e0;
    h[threadIdx.x] = 0; h[threadIdx.x + 256] = 0;
    __syncthreads();
    for (int i = threadIdx.x; i < cnt; i += 256)
        atomicAdd(&h[pk1[e0 + i] & 511], 1);
    __syncthreads();
    // exclusive scan over 512 local-node counts (2 per thread)
    int v0 = h[threadIdx.x * 2], v1 = h[threadIdx.x * 2 + 1];
    int s = v0 + v1;
    ts[threadIdx.x] = s;
    __syncthreads();
    for (int d = 1; d < 256; d <<= 1) {
        int t = (threadIdx.x >= d) ? ts[threadIdx.x - d] : 0;
        __syncthreads();
        ts[threadIdx.x] += t;
        __syncthreads();
    }
    int run = e0 + ts[threadIdx.x] - s;
    int n0 = b * 512 + threadIdx.x * 2;
    cur[threadIdx.x * 2]     = run;
    cur[threadIdx.x * 2 + 1] = run + v0;
    if (n0     <= N_NODES) off[n0]     = run;
    if (n0 + 1 <= N_NODES) off[n0 + 1] = run + v0;
    __syncthreads();
    for (int i = threadIdx.x; i < cnt; i += 256) {
        unsigned int u = pk1[e0 + i];
        int p = atomicAdd(&cur[u & 511], 1);
        eidx[p] = (int)(u >> 9);
    }
}

// ================ dtype conversion (merged x-cvt + weight-cvt) ================
__global__ __launch_bounds__(256) void k_cvtw(const float* __restrict__ X,
    unsigned short* __restrict__ Y,
    const float* __restrict__ Wa, const float* __restrict__ Wb,
    const float* __restrict__ Wc, const float* __restrict__ Wd,
    unsigned short* __restrict__ WT)
{
    int blk = blockIdx.x;
    if (blk < CVT_BLOCKS) {
        int i = blk * 256 + threadIdx.x;
        float4 v = ((const float4*)X)[i];
        ((ushort4*)Y)[i] = make_ushort4(f2bf(v.x), f2bf(v.y), f2bf(v.z), f2bf(v.w));
    } else {
        int idx = (blk - CVT_BLOCKS) * 256 + threadIdx.x;   // 0..65535
        int mat = idx >> 14, w = idx & 16383;
        int k = w >> 7, n = w & 127;
        const float* W = (mat == 0) ? Wa : (mat == 1) ? Wb : (mat == 2) ? Wc : Wd;
        WT[mat * 16384 + n * 128 + k] = f2bf(W[w]);
    }
}

// ================ gather: OUT[n] = f(X[n]) + sum f(X[j]) ================
// (proven round-0/5 structure: sequential node order, register accumulation,
//  16 lanes/node, 8-way edge ILP — do not touch)
template<bool BN>
__device__ inline void acc_row(float* acc, uint4 v,
                               const float* sc, const float* sh)
{
    unsigned int u[4] = {v.x, v.y, v.z, v.w};
    #pragma unroll
    for (int j = 0; j < 4; ++j) {
        float lo = b2f((unsigned short)u[j]);
        float hi = b2f((unsigned short)(u[j] >> 16));
        if (BN) {
            lo = fmaxf(lo * sc[2*j]   + sh[2*j],   0.f);
            hi = fmaxf(hi * sc[2*j+1] + sh[2*j+1], 0.f);
        }
        acc[2*j]   += lo;
        acc[2*j+1] += hi;
    }
}

template<bool BN>
__global__ __launch_bounds__(256) void k_gather(
    const unsigned short* __restrict__ X, const float* __restrict__ SC,
    const int* __restrict__ off, const int* __restrict__ eidx,
    unsigned short* __restrict__ OUT, int M)
{
    int n = blockIdx.x * 16 + (threadIdx.x >> 4);
    if (n >= M) return;
    const int lane = threadIdx.x & 15;
    const size_t co = (size_t)lane * 8;

    float sc[8], sh[8];
    if (BN) {
        *(float4*)&sc[0] = ((const float4*)SC)[lane * 2];
        *(float4*)&sc[4] = ((const float4*)SC)[lane * 2 + 1];
        *(float4*)&sh[0] = ((const float4*)SC)[32 + lane * 2];
        *(float4*)&sh[4] = ((const float4*)SC)[32 + lane * 2 + 1];
    }

    float acc[8] = {0.f, 0.f, 0.f, 0.f, 0.f, 0.f, 0.f, 0.f};
    acc_row<BN>(acc, *(const uint4*)(X + (size_t)n * HID + co), sc, sh);

    int k = off[n], kend = off[n + 1];
    for (; k + 7 < kend; k += 8) {       // 8-way ILP: 128B in flight per lane
        uint4 v0 = *(const uint4*)(X + (size_t)eidx[k]   * HID + co);
        uint4 v1 = *(const uint4*)(X + (size_t)eidx[k+1] * HID + co);
        uint4 v2 = *(const uint4*)(X + (size_t)eidx[k+2] * HID + co);
        uint4 v3 = *(const uint4*)(X + (size_t)eidx[k+3] * HID + co);
        uint4 v4 = *(const uint4*)(X + (size_t)eidx[k+4] * HID + co);
        uint4 v5 = *(const uint4*)(X + (size_t)eidx[k+5] * HID + co);
        uint4 v6 = *(const uint4*)(X + (size_t)eidx[k+6] * HID + co);
        uint4 v7 = *(const uint4*)(X + (size_t)eidx[k+7] * HID + co);
        acc_row<BN>(acc, v0, sc, sh); acc_row<BN>(acc, v1, sc, sh);
        acc_row<BN>(acc, v2, sc, sh); acc_row<BN>(acc, v3, sc, sh);
        acc_row<BN>(acc, v4, sc, sh); acc_row<BN>(acc, v5, sc, sh);
        acc_row<BN>(acc, v6, sc, sh); acc_row<BN>(acc, v7, sc, sh);
    }
    for (; k + 3 < kend; k += 4) {
        uint4 v0 = *(const uint4*)(X + (size_t)eidx[k]   * HID + co);
        uint4 v1 = *(const uint4*)(X + (size_t)eidx[k+1] * HID + co);
        uint4 v2 = *(const uint4*)(X + (size_t)eidx[k+2] * HID + co);
        uint4 v3 = *(const uint4*)(X + (size_t)eidx[k+3] * HID + co);
        acc_row<BN>(acc, v0, sc, sh); acc_row<BN>(acc, v1, sc, sh);
        acc_row<BN>(acc, v2, sc, sh); acc_row<BN>(acc, v3, sc, sh);
    }
    for (; k < kend; ++k) {
        uint4 v = *(const uint4*)(X + (size_t)eidx[k] * HID + co);
        acc_row<BN>(acc, v, sc, sh);
    }

    uint4 o;
    o.x = (unsigned int)f2bf(acc[0]) | ((unsigned int)f2bf(acc[1]) << 16);
    o.y = (unsigned int)f2bf(acc[2]) | ((unsigned int)f2bf(acc[3]) << 16);
    o.z = (unsigned int)f2bf(acc[4]) | ((unsigned int)f2bf(acc[5]) << 16);
    o.w = (unsigned int)f2bf(acc[6]) | ((unsigned int)f2bf(acc[7]) << 16);
    *(uint4*)(OUT + (size_t)n * HID + co) = o;
}

// ============== fused MLP v2.1: weights-in-registers, LDS A/H exchange ==============
// (proven round-5/8: 64-row tile/block, weight frags in 64 VGPR loaded once,
//  A staged to padded LDS, H exchange, LDS C-stage for coalesced stores.
//  Round-9 lesson: keep this body CLEAN — no fences, no finalize tail.)
__global__ __launch_bounds__(256) void k_mlp(
    const unsigned short* __restrict__ A,
    const unsigned short* __restrict__ WTa, const float* __restrict__ ba,
    const unsigned short* __restrict__ WTb, const float* __restrict__ bb,
    unsigned short* __restrict__ Cb, float* __restrict__ Srep, int M)
{
    __shared__ unsigned short Abuf[64 * PS];   // A tile, then C staging
    __shared__ unsigned short Hbuf[64 * PS];   // hidden exchange

    const int tid  = threadIdx.x;
    const int wave = tid >> 6;     // 0..3: owns cols [wave*32, wave*32+32)
    const int lane = tid & 63;
    const int m    = lane & 15;
    const int quad = lane >> 4;
    const int rowbase = blockIdx.x * 64;

    // ---- weight fragments -> registers (once per block) ----
    bf16x8 WA[2][4], WB[2][4];
    float bav[2], bbv[2];
    #pragma unroll
    for (int n0 = 0; n0 < 2; ++n0) {
        const int col = (wave * 2 + n0) * 16 + m;
        const size_t cb = (size_t)col * HID + quad * 8;
        #pragma unroll
        for (int kk = 0; kk < 4; ++kk) {
            WA[n0][kk] = *(const bf16x8*)(WTa + cb + kk * 32);
            WB[n0][kk] = *(const bf16x8*)(WTb + cb + kk * 32);
        }
        bav[n0] = ba[col];
        bbv[n0] = bb[col];
    }

    // ---- stage A tile (64x128 bf16 = 1024 uint4; 4 per thread) ----
    // NOTE: last tile overreads <=31 rows past A's end -> lands in Yb (valid).
    {
        const uint4* Ag = (const uint4*)(A + (size_t)rowbase * HID);
        #pragma unroll
        for (int i = 0; i < 4; ++i) {
            int u = tid + i * 256;
            uint4 v = Ag[u];
            int r = u >> 4, c = u & 15;
            *(uint4*)(Abuf + r * PS + c * 8) = v;
        }
    }
    __syncthreads();

    // ---- GEMM-a ----
    f32x4 acc[4][2];
    #pragma unroll
    for (int rg = 0; rg < 4; ++rg)
        #pragma unroll
        for (int n0 = 0; n0 < 2; ++n0) acc[rg][n0] = {0.f, 0.f, 0.f, 0.f};
    #pragma unroll
    for (int rg = 0; rg < 4; ++rg) {
        #pragma unroll
        for (int kk = 0; kk < 4; ++kk) {
            bf16x8 af = *(const bf16x8*)(Abuf + (rg*16 + m) * PS + quad*8 + kk*32);
            acc[rg][0] = __builtin_amdgcn_mfma_f32_16x16x32_bf16(af, WA[0][kk], acc[rg][0], 0, 0, 0);
            acc[rg][1] = __builtin_amdgcn_mfma_f32_16x16x32_bf16(af, WA[1][kk], acc[rg][1], 0, 0, 0);
        }
    }

    // H = relu(acc + ba) -> Hbuf
    #pragma unroll
    for (int rg = 0; rg < 4; ++rg)
        #pragma unroll
        for (int n0 = 0; n0 < 2; ++n0)
            #pragma unroll
            for (int i = 0; i < 4; ++i)
                Hbuf[(rg*16 + quad*4 + i) * PS + (wave*2 + n0)*16 + m] =
                    f2bf(fmaxf(acc[rg][n0][i] + bav[n0], 0.f));
    __syncthreads();

    // ---- GEMM-b ----
    #pragma unroll
    for (int rg = 0; rg < 4; ++rg)
        #pragma unroll
        for (int n0 = 0; n0 < 2; ++n0) acc[rg][n0] = {0.f, 0.f, 0.f, 0.f};
    #pragma unroll
    for (int rg = 0; rg < 4; ++rg) {
        #pragma unroll
        for (int kk = 0; kk < 4; ++kk) {
            bf16x8 hf = *(const bf16x8*)(Hbuf + (rg*16 + m) * PS + quad*8 + kk*32);
            acc[rg][0] = __builtin_amdgcn_mfma_f32_16x16x32_bf16(hf, WB[0][kk], acc[rg][0], 0, 0, 0);
            acc[rg][1] = __builtin_amdgcn_mfma_f32_16x16x32_bf16(hf, WB[1][kk], acc[rg][1], 0, 0, 0);
        }
    }

    // ---- epilogue: bias, BN stats, C-stage into Abuf ----
    const bool full = (rowbase + 64 <= M);
    float s[2] = {0.f, 0.f}, s2[2] = {0.f, 0.f};
    #pragma unroll
    for (int rg = 0; rg < 4; ++rg) {
        #pragma unroll
        for (int n0 = 0; n0 < 2; ++n0) {
            #pragma unroll
            for (int i = 0; i < 4; ++i) {
                float v = acc[rg][n0][i] + bbv[n0];
                if (full || rowbase + rg*16 + quad*4 + i < M) { s[n0] += v; s2[n0] += v*v; }
                Abuf[(rg*16 + quad*4 + i) * PS + (wave*2 + n0)*16 + m] = f2bf(v);
            }
        }
    }
    __syncthreads();

    // ---- coalesced C store (1024 uint4; 4 per thread) ----
    #pragma unroll
    for (int i = 0; i < 4; ++i) {
        int u = tid + i * 256;
        int r = u >> 4, c = u & 15;
        uint4 v = *(const uint4*)(Abuf + r * PS + c * 8);
        int g = rowbase + r;
        if (g < M) *(uint4*)(Cb + (size_t)g * HID + c * 8) = v;
    }

    // ---- BN stats: reduce over quads, atomics into replicas ----
    #pragma unroll
    for (int n0 = 0; n0 < 2; ++n0) {
        s[n0]  += __shfl_xor(s[n0], 16, 64);
        s[n0]  += __shfl_xor(s[n0], 32, 64);
        s2[n0] += __shfl_xor(s2[n0], 16, 64);
        s2[n0] += __shfl_xor(s2[n0], 32, 64);
    }
    if (quad == 0) {
        float* R = Srep + (size_t)((blockIdx.x * 4 + wave) & (NREP - 1)) * 256;
        #pragma unroll
        for (int n0 = 0; n0 < 2; ++n0) {
            int col = (wave * 2 + n0) * 16 + m;
            atomicAdd(&R[col], s[n0]);
            atomicAdd(&R[128 + col], s2[n0]);
        }
    }
}

__global__ void k_bnfinalize(const float* __restrict__ Srep,
    const float* __restrict__ gamma, const float* __restrict__ beta,
    float* __restrict__ SC, int M)
{
    int f = threadIdx.x;   // 128
    float s = 0.f, s2 = 0.f;
    for (int r = 0; r < NREP; ++r) {
        s += Srep[r * 256 + f];
        s2 += Srep[r * 256 + 128 + f];
    }
    float mean = s / (float)M;
    float var = s2 / (float)M - mean * mean;
    var = fmaxf(var, 0.f);
    float sc = gamma[f] * rsqrtf(var + BN_EPS);
    SC[f] = sc;
    SC[HID + f] = beta[f] - mean * sc;
}

// ---------------- fused pooling (BN+ReLU) + classifier head ----------------
// (verified-correct in round-9; one 512-thread block per graph. Removes the
//  P buffer, its memset, and the separate k_head launch.)
__global__ __launch_bounds__(512) void k_poolhead(
    const unsigned short* __restrict__ H, const float* __restrict__ SC,
    const int* __restrict__ gstart, const float* __restrict__ Wlin,
    const float* __restrict__ blin, float* __restrict__ out)
{
    __shared__ float ls[512];
    __shared__ float pooled[128];
    int g = blockIdx.x;
    int beg = gstart[g], end = gstart[g + 1];
    int f = threadIdx.x & 127, q = threadIdx.x >> 7;   // q in 0..3
    float scv = SC[f], shv = SC[HID + f];
    float s = 0.f;
    for (int r = beg + q; r < end; r += 4)
        s += fmaxf(b2f(H[(size_t)r * HID + f]) * scv + shv, 0.f);
    ls[threadIdx.x] = s;
    __syncthreads();
    if (threadIdx.x < 128)
        pooled[threadIdx.x] = ls[threadIdx.x] + ls[threadIdx.x + 128]
                            + ls[threadIdx.x + 256] + ls[threadIdx.x + 384];
    __syncthreads();
    if (threadIdx.x < 64) {
        int l = threadIdx.x;
        float inv = 1.f / (float)max(end - beg, 1);
        float p0 = pooled[l] * inv;
        float p1 = pooled[64 + l] * inv;
        float lg[10];
        #pragma unroll
        for (int c = 0; c < 10; ++c) {
            float v = p0 * Wlin[l * 10 + c] + p1 * Wlin[(64 + l) * 10 + c];
            #pragma unroll
            for (int o = 32; o > 0; o >>= 1) v += __shfl_down(v, o);
            lg[c] = v;
        }
        if (l == 0) {
            float mx = -1e30f;
            #pragma unroll
            for (int c = 0; c < 10; ++c) { lg[c] += blin[c]; mx = fmaxf(mx, lg[c]); }
            float se = 0.f;
            #pragma unroll
            for (int c = 0; c < 10; ++c) se += expf(lg[c] - mx);
            float lse = mx + logf(se);
            #pragma unroll
            for (int c = 0; c < 10; ++c) out[g * 10 + c] = lg[c] - lse;
        }
    }
}

extern "C" void kernel_launch(void* const* d_in, const int* in_sizes, int n_in,
                              void* d_out, int out_size, void* d_ws, size_t ws_size,
                              hipStream_t stream)
{
    const float* x    = (const float*)d_in[0];
    const int*   ei   = (const int*)d_in[1];
    const int*   batch= (const int*)d_in[2];
    const float* W1a  = (const float*)d_in[3];
    const float* b1a  = (const float*)d_in[4];
    const float* W1b  = (const float*)d_in[5];
    const float* b1b  = (const float*)d_in[6];
    const float* g1   = (const float*)d_in[7];
    const float* be1  = (const float*)d_in[8];
    const float* W2a  = (const float*)d_in[9];
    const float* b2a  = (const float*)d_in[10];
    const float* W2b  = (const float*)d_in[11];
    const float* b2b  = (const float*)d_in[12];
    const float* g2   = (const float*)d_in[13];
    const float* be2  = (const float*)d_in[14];
    const float* Wl   = (const float*)d_in[15];
    const float* bl   = (const float*)d_in[16];
    float* out = (float*)d_out;

    const int* src = ei;
    const int* dst = ei + N_EDGESC;

    const size_t NM = (size_t)N_NODES * HID;    // 12.8M
    char* wsb = (char*)d_ws;
    // Ab first: k_mlp overreads <=31 rows past Ab -> lands in Yb (valid).
    unsigned short* Ab  = (unsigned short*)wsb;                 // NM u16 (agg out)
    unsigned short* Yb  = Ab + NM;                              // NM u16 (Cb1)
    unsigned short* Xb  = Yb + NM;                              // NM u16 (x / Cb2)
    // Srep1|Srep2 contiguous -> single memset
    float* Srep1 = (float*)(Xb + NM);                           // NREP*256
    float* Srep2 = Srep1 + NREP * 256;                          // NREP*256
    float* SC1  = Srep2 + NREP * 256;                           // 256
    float* SC2  = SC1 + 256;                                    // 256
    unsigned short* WT = (unsigned short*)(SC2 + 256);          // 4*16384 u16
    int* hist   = (int*)(WT + 4 * 16384);                       // HISTN
    int* eidx   = hist + HISTN;                                 // N_EDGESC
    int* off    = eidx + N_EDGESC;                              // N_NODES+1
    int* bsum   = off + N_NODES + 1;                            // 64
    int* gstart = bsum + 64;                                    // NGRAPH+1
    // pk1 aliases Xb: dead before k_cvtw writes Xb (launch order below).
    unsigned int* pk1 = (unsigned int*)Xb;                      // N_EDGESC

    dim3 blk(256);
    const int gatBlocks = (N_NODES + 15) / 16;         // 6250

    // single memset: Srep1+Srep2 (contiguous)
    hipMemsetAsync(Srep1, 0, 2 * NREP * 256 * sizeof(float), stream);

    // ---- atomic-free edge partition -> per-node CSR ----
    k_phist<<<PBLK, blk, 0, stream>>>(dst, hist);
    k_scan_block<<<HSCAN_BLOCKS, blk, 0, stream>>>(hist, bsum, HISTN);
    k_scan_top_bounds<<<1, 128, 0, stream>>>(bsum, HSCAN_BLOCKS, batch, gstart);
    k_pscatter<<<PBLK, blk, 0, stream>>>(src, dst, hist, bsum, pk1);
    k_psort<<<NCOARSE, blk, 0, stream>>>(pk1, hist, bsum, eidx, off);

    // ---- conversions (after k_psort: k_cvtw overwrites pk1's alias region) ----
    k_cvtw<<<CVT_BLOCKS + 256, blk, 0, stream>>>(x, Xb, W1a, W1b, W2a, W2b, WT);

    // ---- conv1 ----
    k_gather<false><<<gatBlocks, blk, 0, stream>>>(Xb, nullptr, off, eidx, Ab, N_NODES);
    k_mlp<<<MLP_BLOCKS, blk, 0, stream>>>(Ab, WT, b1a, WT + 16384, b1b, Yb, Srep1, N_NODES);
    k_bnfinalize<<<1, 128, 0, stream>>>(Srep1, g1, be1, SC1, N_NODES);

    // ---- conv2 (BN1+ReLU fused into gather) ----
    k_gather<true><<<gatBlocks, blk, 0, stream>>>(Yb, SC1, off, eidx, Ab, N_NODES);
    k_mlp<<<MLP_BLOCKS, blk, 0, stream>>>(Ab, WT + 2 * 16384, b2a, WT + 3 * 16384, b2b, Xb, Srep2, N_NODES);
    k_bnfinalize<<<1, 128, 0, stream>>>(Srep2, g2, be2, SC2, N_NODES);

    // ---- fused pool (BN2+ReLU) + head ----
    k_poolhead<<<NGRAPH, 512, 0, stream>>>(Xb, SC2, gstart, Wl, bl, out);
}

// Round 11
// 302.196 us; speedup vs baseline: 2.5142x; 1.1482x over previous
//
#include <hip/hip_runtime.h>

#define N_NODES 100000
#define N_EDGESC 800000
#define HID 128
#define NGRAPH 128
#define BN_EPS 1e-5f
#define NREP 32    // BN-stats atomic replicas
#define PS 136     // LDS row stride in shorts: 272B = 16B-aligned, <=2-way banks
#define MLP_BLOCKS ((N_NODES + 63) / 64)   // 1563 tiles, one per block

// ---- atomic-free edge partition parameters ----
#define PBLK 256                     // partition blocks
#define PCHUNK 3125                  // edges per partition block (256*3125 = 800000 exact)
#define NCOARSE 196                  // 512-node coarse buckets: bin = dst>>9 (196*512 >= 100000)
#define HISTN (NCOARSE * PBLK)       // 50176
#define HSCAN_BLOCKS (HISTN / 1024)  // 49 exact
#define CVT_BLOCKS 12500             // 3200000 float4 / 256

typedef __bf16 bf16x8 __attribute__((ext_vector_type(8)));
typedef float f32x4 __attribute__((ext_vector_type(4)));

__device__ inline unsigned short f2bf(float f) {     // RNE fp32 -> bf16
    unsigned int u = __float_as_uint(f);
    unsigned int r = u + 0x7FFFu + ((u >> 16) & 1u);
    return (unsigned short)(r >> 16);
}
__device__ inline float b2f(unsigned short u) {
    return __uint_as_float(((unsigned int)u) << 16);
}

// ================= atomic-free bucket partition =================
// JOURNAL: LDS *int* atomics native & cheap; LDS *float* atomicAdd = CAS
// loop disaster (round-1). Round-6: don't fuse gather into MLP (occupancy).
// Round-7: degree-sort perm regressed (locality loss). Round-9: last-block
// BN-finalize (__threadfence in hot epilogue) and cooperative grid.sync
// mega-kernel both regressed. Round-10: single-block-per-graph poolhead =
// 62us vs split pool+head ~12us — fusing across a reduction boundary killed
// grid parallelism (128 blocks, 8.6% occupancy). ALL REVERTED — this is the
// proven round-8 structure (303.6us measured).

__global__ __launch_bounds__(256) void k_phist(const int* __restrict__ dst,
                                               int* __restrict__ hist)
{
    __shared__ int h[NCOARSE];
    if (threadIdx.x < NCOARSE) h[threadIdx.x] = 0;
    __syncthreads();
    int base = blockIdx.x * PCHUNK;
    for (int i = threadIdx.x; i < PCHUNK; i += 256)
        atomicAdd(&h[dst[base + i] >> 9], 1);
    __syncthreads();
    if (threadIdx.x < NCOARSE)
        hist[threadIdx.x * PBLK + blockIdx.x] = h[threadIdx.x];
}

// generic exclusive-scan (in-place), 1024 elements per block
__global__ __launch_bounds__(256) void k_scan_block(int* __restrict__ a,
    int* __restrict__ bsum, int n)
{
    __shared__ int ts[256];
    int base = blockIdx.x * 1024 + threadIdx.x * 4;
    int v[4], s = 0;
    #pragma unroll
    for (int i = 0; i < 4; ++i) {
        int idx = base + i;
        v[i] = (idx < n) ? a[idx] : 0;
        s += v[i];
    }
    ts[threadIdx.x] = s;
    __syncthreads();
    for (int d = 1; d < 256; d <<= 1) {
        int t = (threadIdx.x >= d) ? ts[threadIdx.x - d] : 0;
        __syncthreads();
        ts[threadIdx.x] += t;
        __syncthreads();
    }
    int run = ts[threadIdx.x] - s;
    #pragma unroll
    for (int i = 0; i < 4; ++i) {
        int idx = base + i;
        if (idx < n) a[idx] = run;
        run += v[i];
    }
    if (threadIdx.x == 255) bsum[blockIdx.x] = ts[255];
}

// merged: serial top-level scan (lane 0) + per-graph bounds (all 128 lanes)
__global__ void k_scan_top_bounds(int* __restrict__ bsum, int nb,
    const int* __restrict__ batch, int* __restrict__ gstart)
{
    if (threadIdx.x == 0) {
        int run = 0;
        for (int i = 0; i < nb; ++i) { int t = bsum[i]; bsum[i] = run; run += t; }
    }
    int g = threadIdx.x;   // 128
    int lo = 0, hi = N_NODES;
    while (lo < hi) {
        int mid = (lo + hi) >> 1;
        if (batch[mid] < g) lo = mid + 1; else hi = mid;
    }
    gstart[g] = lo;
    if (g == 0) gstart[NGRAPH] = N_NODES;
}

// P1b: scatter into coarse buckets. LDS int cursors; bsum added inline.
// pk = (src<<9)|(dst&511).
__global__ __launch_bounds__(256) void k_pscatter(const int* __restrict__ src,
    const int* __restrict__ dst, const int* __restrict__ hist,
    const int* __restrict__ bsum, unsigned int* __restrict__ pk1)
{
    __shared__ int cur[NCOARSE];
    if (threadIdx.x < NCOARSE) {
        int idx = threadIdx.x * PBLK + blockIdx.x;
        cur[threadIdx.x] = hist[idx] + bsum[idx >> 10];
    }
    __syncthreads();
    int base = blockIdx.x * PCHUNK;
    for (int i = threadIdx.x; i < PCHUNK; i += 256) {
        int s = src[base + i], d = dst[base + i];
        int p = atomicAdd(&cur[d >> 9], 1);
        pk1[p] = ((unsigned int)s << 9) | (unsigned int)(d & 511);
    }
}

// P2: per-node counting sort within each coarse bucket (~4096 edges).
// Emits CSR: eidx (sorted by dst node) + off[n]. LDS int atomics only.
__global__ __launch_bounds__(256) void k_psort(const unsigned int* __restrict__ pk1,
    const int* __restrict__ hist, const int* __restrict__ bsum,
    int* __restrict__ eidx, int* __restrict__ off)
{
    __shared__ int h[512], cur[512], ts[256];
    const int b = blockIdx.x;   // 196
    const int i0 = b * PBLK;
    const int e0 = hist[i0] + bsum[i0 >> 10];
    int e1 = N_EDGESC;
    if (b < NCOARSE - 1) {
        const int i1 = (b + 1) * PBLK;
        e1 = hist[i1] + bsum[i1 >> 10];
    }
    const int cnt = e1 - e0;
    h[threadIdx.x] = 0; h[threadIdx.x + 256] = 0;
    __syncthreads();
    for (int i = threadIdx.x; i < cnt; i += 256)
        atomicAdd(&h[pk1[e0 + i] & 511], 1);
    __syncthreads();
    // exclusive scan over 512 local-node counts (2 per thread)
    int v0 = h[threadIdx.x * 2], v1 = h[threadIdx.x * 2 + 1];
    int s = v0 + v1;
    ts[threadIdx.x] = s;
    __syncthreads();
    for (int d = 1; d < 256; d <<= 1) {
        int t = (threadIdx.x >= d) ? ts[threadIdx.x - d] : 0;
        __syncthreads();
        ts[threadIdx.x] += t;
        __syncthreads();
    }
    int run = e0 + ts[threadIdx.x] - s;
    int n0 = b * 512 + threadIdx.x * 2;
    cur[threadIdx.x * 2]     = run;
    cur[threadIdx.x * 2 + 1] = run + v0;
    if (n0     <= N_NODES) off[n0]     = run;
    if (n0 + 1 <= N_NODES) off[n0 + 1] = run + v0;
    __syncthreads();
    for (int i = threadIdx.x; i < cnt; i += 256) {
        unsigned int u = pk1[e0 + i];
        int p = atomicAdd(&cur[u & 511], 1);
        eidx[p] = (int)(u >> 9);
    }
}

// ================ dtype conversion (merged x-cvt + weight-cvt) ================
__global__ __launch_bounds__(256) void k_cvtw(const float* __restrict__ X,
    unsigned short* __restrict__ Y,
    const float* __restrict__ Wa, const float* __restrict__ Wb,
    const float* __restrict__ Wc, const float* __restrict__ Wd,
    unsigned short* __restrict__ WT)
{
    int blk = blockIdx.x;
    if (blk < CVT_BLOCKS) {
        int i = blk * 256 + threadIdx.x;
        float4 v = ((const float4*)X)[i];
        ((ushort4*)Y)[i] = make_ushort4(f2bf(v.x), f2bf(v.y), f2bf(v.z), f2bf(v.w));
    } else {
        int idx = (blk - CVT_BLOCKS) * 256 + threadIdx.x;   // 0..65535
        int mat = idx >> 14, w = idx & 16383;
        int k = w >> 7, n = w & 127;
        const float* W = (mat == 0) ? Wa : (mat == 1) ? Wb : (mat == 2) ? Wc : Wd;
        WT[mat * 16384 + n * 128 + k] = f2bf(W[w]);
    }
}

// ================ gather: OUT[n] = f(X[n]) + sum f(X[j]) ================
// (proven round-0/5 structure: sequential node order, register accumulation,
//  16 lanes/node, 8-way edge ILP — do not touch)
template<bool BN>
__device__ inline void acc_row(float* acc, uint4 v,
                               const float* sc, const float* sh)
{
    unsigned int u[4] = {v.x, v.y, v.z, v.w};
    #pragma unroll
    for (int j = 0; j < 4; ++j) {
        float lo = b2f((unsigned short)u[j]);
        float hi = b2f((unsigned short)(u[j] >> 16));
        if (BN) {
            lo = fmaxf(lo * sc[2*j]   + sh[2*j],   0.f);
            hi = fmaxf(hi * sc[2*j+1] + sh[2*j+1], 0.f);
        }
        acc[2*j]   += lo;
        acc[2*j+1] += hi;
    }
}

template<bool BN>
__global__ __launch_bounds__(256) void k_gather(
    const unsigned short* __restrict__ X, const float* __restrict__ SC,
    const int* __restrict__ off, const int* __restrict__ eidx,
    unsigned short* __restrict__ OUT, int M)
{
    int n = blockIdx.x * 16 + (threadIdx.x >> 4);
    if (n >= M) return;
    const int lane = threadIdx.x & 15;
    const size_t co = (size_t)lane * 8;

    float sc[8], sh[8];
    if (BN) {
        *(float4*)&sc[0] = ((const float4*)SC)[lane * 2];
        *(float4*)&sc[4] = ((const float4*)SC)[lane * 2 + 1];
        *(float4*)&sh[0] = ((const float4*)SC)[32 + lane * 2];
        *(float4*)&sh[4] = ((const float4*)SC)[32 + lane * 2 + 1];
    }

    float acc[8] = {0.f, 0.f, 0.f, 0.f, 0.f, 0.f, 0.f, 0.f};
    acc_row<BN>(acc, *(const uint4*)(X + (size_t)n * HID + co), sc, sh);

    int k = off[n], kend = off[n + 1];
    for (; k + 7 < kend; k += 8) {       // 8-way ILP: 128B in flight per lane
        uint4 v0 = *(const uint4*)(X + (size_t)eidx[k]   * HID + co);
        uint4 v1 = *(const uint4*)(X + (size_t)eidx[k+1] * HID + co);
        uint4 v2 = *(const uint4*)(X + (size_t)eidx[k+2] * HID + co);
        uint4 v3 = *(const uint4*)(X + (size_t)eidx[k+3] * HID + co);
        uint4 v4 = *(const uint4*)(X + (size_t)eidx[k+4] * HID + co);
        uint4 v5 = *(const uint4*)(X + (size_t)eidx[k+5] * HID + co);
        uint4 v6 = *(const uint4*)(X + (size_t)eidx[k+6] * HID + co);
        uint4 v7 = *(const uint4*)(X + (size_t)eidx[k+7] * HID + co);
        acc_row<BN>(acc, v0, sc, sh); acc_row<BN>(acc, v1, sc, sh);
        acc_row<BN>(acc, v2, sc, sh); acc_row<BN>(acc, v3, sc, sh);
        acc_row<BN>(acc, v4, sc, sh); acc_row<BN>(acc, v5, sc, sh);
        acc_row<BN>(acc, v6, sc, sh); acc_row<BN>(acc, v7, sc, sh);
    }
    for (; k + 3 < kend; k += 4) {
        uint4 v0 = *(const uint4*)(X + (size_t)eidx[k]   * HID + co);
        uint4 v1 = *(const uint4*)(X + (size_t)eidx[k+1] * HID + co);
        uint4 v2 = *(const uint4*)(X + (size_t)eidx[k+2] * HID + co);
        uint4 v3 = *(const uint4*)(X + (size_t)eidx[k+3] * HID + co);
        acc_row<BN>(acc, v0, sc, sh); acc_row<BN>(acc, v1, sc, sh);
        acc_row<BN>(acc, v2, sc, sh); acc_row<BN>(acc, v3, sc, sh);
    }
    for (; k < kend; ++k) {
        uint4 v = *(const uint4*)(X + (size_t)eidx[k] * HID + co);
        acc_row<BN>(acc, v, sc, sh);
    }

    uint4 o;
    o.x = (unsigned int)f2bf(acc[0]) | ((unsigned int)f2bf(acc[1]) << 16);
    o.y = (unsigned int)f2bf(acc[2]) | ((unsigned int)f2bf(acc[3]) << 16);
    o.z = (unsigned int)f2bf(acc[4]) | ((unsigned int)f2bf(acc[5]) << 16);
    o.w = (unsigned int)f2bf(acc[6]) | ((unsigned int)f2bf(acc[7]) << 16);
    *(uint4*)(OUT + (size_t)n * HID + co) = o;
}

// ============== fused MLP v2.1: weights-in-registers, LDS A/H exchange ==============
// (proven round-5/8: 64-row tile/block, weight frags in 64 VGPR loaded once,
//  A staged to padded LDS, H exchange, LDS C-stage for coalesced stores.
//  Round-9 lesson: keep this body CLEAN — no fences, no finalize tail.)
__global__ __launch_bounds__(256) void k_mlp(
    const unsigned short* __restrict__ A,
    const unsigned short* __restrict__ WTa, const float* __restrict__ ba,
    const unsigned short* __restrict__ WTb, const float* __restrict__ bb,
    unsigned short* __restrict__ Cb, float* __restrict__ Srep, int M)
{
    __shared__ unsigned short Abuf[64 * PS];   // A tile, then C staging
    __shared__ unsigned short Hbuf[64 * PS];   // hidden exchange

    const int tid  = threadIdx.x;
    const int wave = tid >> 6;     // 0..3: owns cols [wave*32, wave*32+32)
    const int lane = tid & 63;
    const int m    = lane & 15;
    const int quad = lane >> 4;
    const int rowbase = blockIdx.x * 64;

    // ---- weight fragments -> registers (once per block) ----
    bf16x8 WA[2][4], WB[2][4];
    float bav[2], bbv[2];
    #pragma unroll
    for (int n0 = 0; n0 < 2; ++n0) {
        const int col = (wave * 2 + n0) * 16 + m;
        const size_t cb = (size_t)col * HID + quad * 8;
        #pragma unroll
        for (int kk = 0; kk < 4; ++kk) {
            WA[n0][kk] = *(const bf16x8*)(WTa + cb + kk * 32);
            WB[n0][kk] = *(const bf16x8*)(WTb + cb + kk * 32);
        }
        bav[n0] = ba[col];
        bbv[n0] = bb[col];
    }

    // ---- stage A tile (64x128 bf16 = 1024 uint4; 4 per thread) ----
    // NOTE: last tile overreads <=31 rows past A's end -> lands in Yb (valid).
    {
        const uint4* Ag = (const uint4*)(A + (size_t)rowbase * HID);
        #pragma unroll
        for (int i = 0; i < 4; ++i) {
            int u = tid + i * 256;
            uint4 v = Ag[u];
            int r = u >> 4, c = u & 15;
            *(uint4*)(Abuf + r * PS + c * 8) = v;
        }
    }
    __syncthreads();

    // ---- GEMM-a ----
    f32x4 acc[4][2];
    #pragma unroll
    for (int rg = 0; rg < 4; ++rg)
        #pragma unroll
        for (int n0 = 0; n0 < 2; ++n0) acc[rg][n0] = {0.f, 0.f, 0.f, 0.f};
    #pragma unroll
    for (int rg = 0; rg < 4; ++rg) {
        #pragma unroll
        for (int kk = 0; kk < 4; ++kk) {
            bf16x8 af = *(const bf16x8*)(Abuf + (rg*16 + m) * PS + quad*8 + kk*32);
            acc[rg][0] = __builtin_amdgcn_mfma_f32_16x16x32_bf16(af, WA[0][kk], acc[rg][0], 0, 0, 0);
            acc[rg][1] = __builtin_amdgcn_mfma_f32_16x16x32_bf16(af, WA[1][kk], acc[rg][1], 0, 0, 0);
        }
    }

    // H = relu(acc + ba) -> Hbuf
    #pragma unroll
    for (int rg = 0; rg < 4; ++rg)
        #pragma unroll
        for (int n0 = 0; n0 < 2; ++n0)
            #pragma unroll
            for (int i = 0; i < 4; ++i)
                Hbuf[(rg*16 + quad*4 + i) * PS + (wave*2 + n0)*16 + m] =
                    f2bf(fmaxf(acc[rg][n0][i] + bav[n0], 0.f));
    __syncthreads();

    // ---- GEMM-b ----
    #pragma unroll
    for (int rg = 0; rg < 4; ++rg)
        #pragma unroll
        for (int n0 = 0; n0 < 2; ++n0) acc[rg][n0] = {0.f, 0.f, 0.f, 0.f};
    #pragma unroll
    for (int rg = 0; rg < 4; ++rg) {
        #pragma unroll
        for (int kk = 0; kk < 4; ++kk) {
            bf16x8 hf = *(const bf16x8*)(Hbuf + (rg*16 + m) * PS + quad*8 + kk*32);
            acc[rg][0] = __builtin_amdgcn_mfma_f32_16x16x32_bf16(hf, WB[0][kk], acc[rg][0], 0, 0, 0);
            acc[rg][1] = __builtin_amdgcn_mfma_f32_16x16x32_bf16(hf, WB[1][kk], acc[rg][1], 0, 0, 0);
        }
    }

    // ---- epilogue: bias, BN stats, C-stage into Abuf ----
    const bool full = (rowbase + 64 <= M);
    float s[2] = {0.f, 0.f}, s2[2] = {0.f, 0.f};
    #pragma unroll
    for (int rg = 0; rg < 4; ++rg) {
        #pragma unroll
        for (int n0 = 0; n0 < 2; ++n0) {
            #pragma unroll
            for (int i = 0; i < 4; ++i) {
                float v = acc[rg][n0][i] + bbv[n0];
                if (full || rowbase + rg*16 + quad*4 + i < M) { s[n0] += v; s2[n0] += v*v; }
                Abuf[(rg*16 + quad*4 + i) * PS + (wave*2 + n0)*16 + m] = f2bf(v);
            }
        }
    }
    __syncthreads();

    // ---- coalesced C store (1024 uint4; 4 per thread) ----
    #pragma unroll
    for (int i = 0; i < 4; ++i) {
        int u = tid + i * 256;
        int r = u >> 4, c = u & 15;
        uint4 v = *(const uint4*)(Abuf + r * PS + c * 8);
        int g = rowbase + r;
        if (g < M) *(uint4*)(Cb + (size_t)g * HID + c * 8) = v;
    }

    // ---- BN stats: reduce over quads, atomics into replicas ----
    #pragma unroll
    for (int n0 = 0; n0 < 2; ++n0) {
        s[n0]  += __shfl_xor(s[n0], 16, 64);
        s[n0]  += __shfl_xor(s[n0], 32, 64);
        s2[n0] += __shfl_xor(s2[n0], 16, 64);
        s2[n0] += __shfl_xor(s2[n0], 32, 64);
    }
    if (quad == 0) {
        float* R = Srep + (size_t)((blockIdx.x * 4 + wave) & (NREP - 1)) * 256;
        #pragma unroll
        for (int n0 = 0; n0 < 2; ++n0) {
            int col = (wave * 2 + n0) * 16 + m;
            atomicAdd(&R[col], s[n0]);
            atomicAdd(&R[128 + col], s2[n0]);
        }
    }
}

__global__ void k_bnfinalize(const float* __restrict__ Srep,
    const float* __restrict__ gamma, const float* __restrict__ beta,
    float* __restrict__ SC, int M)
{
    int f = threadIdx.x;   // 128
    float s = 0.f, s2 = 0.f;
    for (int r = 0; r < NREP; ++r) {
        s += Srep[r * 256 + f];
        s2 += Srep[r * 256 + 128 + f];
    }
    float mean = s / (float)M;
    float var = s2 / (float)M - mean * mean;
    var = fmaxf(var, 0.f);
    float sc = gamma[f] * rsqrtf(var + BN_EPS);
    SC[f] = sc;
    SC[HID + f] = beta[f] - mean * sc;
}

// ---------------- pooling (fused BN+ReLU), 16 parts per graph ----------------
// (proven round-8: 2048 blocks keep all CUs busy; atomicAdd into P)
__global__ __launch_bounds__(256) void k_pool(const unsigned short* __restrict__ H,
    const float* __restrict__ SC, const int* __restrict__ gstart,
    float* __restrict__ P)
{
    int g = blockIdx.x >> 4, part = blockIdx.x & 15;
    int beg = gstart[g], end = gstart[g + 1];
    int f = threadIdx.x & 127, half = threadIdx.x >> 7;
    float sc = SC[f], sh = SC[HID + f];
    float s = 0.f;
    for (int r = beg + part * 2 + half; r < end; r += 32)
        s += fmaxf(b2f(H[(size_t)r * HID + f]) * sc + sh, 0.f);
    __shared__ float ls[256];
    ls[threadIdx.x] = s;
    __syncthreads();
    if (threadIdx.x < 128)
        atomicAdd(&P[g * HID + threadIdx.x], ls[threadIdx.x] + ls[threadIdx.x + 128]);
}

// ---------------- classifier head + log_softmax ----------------
__global__ void k_head(const float* __restrict__ P, const int* __restrict__ gstart,
    const float* __restrict__ Wlin, const float* __restrict__ blin,
    float* __restrict__ out)
{
    int g = blockIdx.x;
    int l = threadIdx.x;    // 64 lanes
    float inv = 1.f / (float)max(gstart[g + 1] - gstart[g], 1);
    float p0 = P[(size_t)g * HID + l] * inv;
    float p1 = P[(size_t)g * HID + 64 + l] * inv;
    float lg[10];
    #pragma unroll
    for (int c = 0; c < 10; ++c) {
        float v = p0 * Wlin[l * 10 + c] + p1 * Wlin[(64 + l) * 10 + c];
        #pragma unroll
        for (int off = 32; off > 0; off >>= 1) v += __shfl_down(v, off);
        lg[c] = v;
    }
    if (l == 0) {
        float mx = -1e30f;
        #pragma unroll
        for (int c = 0; c < 10; ++c) { lg[c] += blin[c]; mx = fmaxf(mx, lg[c]); }
        float s = 0.f;
        #pragma unroll
        for (int c = 0; c < 10; ++c) s += expf(lg[c] - mx);
        float lse = mx + logf(s);
        #pragma unroll
        for (int c = 0; c < 10; ++c) out[g * 10 + c] = lg[c] - lse;
    }
}

extern "C" void kernel_launch(void* const* d_in, const int* in_sizes, int n_in,
                              void* d_out, int out_size, void* d_ws, size_t ws_size,
                              hipStream_t stream)
{
    const float* x    = (const float*)d_in[0];
    const int*   ei   = (const int*)d_in[1];
    const int*   batch= (const int*)d_in[2];
    const float* W1a  = (const float*)d_in[3];
    const float* b1a  = (const float*)d_in[4];
    const float* W1b  = (const float*)d_in[5];
    const float* b1b  = (const float*)d_in[6];
    const float* g1   = (const float*)d_in[7];
    const float* be1  = (const float*)d_in[8];
    const float* W2a  = (const float*)d_in[9];
    const float* b2a  = (const float*)d_in[10];
    const float* W2b  = (const float*)d_in[11];
    const float* b2b  = (const float*)d_in[12];
    const float* g2   = (const float*)d_in[13];
    const float* be2  = (const float*)d_in[14];
    const float* Wl   = (const float*)d_in[15];
    const float* bl   = (const float*)d_in[16];
    float* out = (float*)d_out;

    const int* src = ei;
    const int* dst = ei + N_EDGESC;

    const size_t NM = (size_t)N_NODES * HID;    // 12.8M
    char* wsb = (char*)d_ws;
    // Ab first: k_mlp overreads <=31 rows past Ab -> lands in Yb (valid).
    unsigned short* Ab  = (unsigned short*)wsb;                 // NM u16 (agg out)
    unsigned short* Yb  = Ab + NM;                              // NM u16 (Cb1)
    unsigned short* Xb  = Yb + NM;                              // NM u16 (x / Cb2)
    // Srep1|Srep2|P contiguous -> single memset
    float* Srep1 = (float*)(Xb + NM);                           // NREP*256
    float* Srep2 = Srep1 + NREP * 256;                          // NREP*256
    float* P    = Srep2 + NREP * 256;                           // 128*128
    float* SC1  = P + (size_t)NGRAPH * HID;                     // 256
    float* SC2  = SC1 + 256;                                    // 256
    unsigned short* WT = (unsigned short*)(SC2 + 256);          // 4*16384 u16
    int* hist   = (int*)(WT + 4 * 16384);                       // HISTN
    int* eidx   = hist + HISTN;                                 // N_EDGESC
    int* off    = eidx + N_EDGESC;                              // N_NODES+1
    int* bsum   = off + N_NODES + 1;                            // 64
    int* gstart = bsum + 64;                                    // NGRAPH+1
    // pk1 aliases Xb: dead before k_cvtw writes Xb (launch order below).
    unsigned int* pk1 = (unsigned int*)Xb;                      // N_EDGESC

    dim3 blk(256);
    const int gatBlocks = (N_NODES + 15) / 16;         // 6250

    // single memset: Srep1+Srep2+P (contiguous)
    hipMemsetAsync(Srep1, 0,
        (2 * NREP * 256 + (size_t)NGRAPH * HID) * sizeof(float), stream);

    // ---- atomic-free edge partition -> per-node CSR ----
    k_phist<<<PBLK, blk, 0, stream>>>(dst, hist);
    k_scan_block<<<HSCAN_BLOCKS, blk, 0, stream>>>(hist, bsum, HISTN);
    k_scan_top_bounds<<<1, 128, 0, stream>>>(bsum, HSCAN_BLOCKS, batch, gstart);
    k_pscatter<<<PBLK, blk, 0, stream>>>(src, dst, hist, bsum, pk1);
    k_psort<<<NCOARSE, blk, 0, stream>>>(pk1, hist, bsum, eidx, off);

    // ---- conversions (after k_psort: k_cvtw overwrites pk1's alias region) ----
    k_cvtw<<<CVT_BLOCKS + 256, blk, 0, stream>>>(x, Xb, W1a, W1b, W2a, W2b, WT);

    // ---- conv1 ----
    k_gather<false><<<gatBlocks, blk, 0, stream>>>(Xb, nullptr, off, eidx, Ab, N_NODES);
    k_mlp<<<MLP_BLOCKS, blk, 0, stream>>>(Ab, WT, b1a, WT + 16384, b1b, Yb, Srep1, N_NODES);
    k_bnfinalize<<<1, 128, 0, stream>>>(Srep1, g1, be1, SC1, N_NODES);

    // ---- conv2 (BN1+ReLU fused into gather) ----
    k_gather<true><<<gatBlocks, blk, 0, stream>>>(Yb, SC1, off, eidx, Ab, N_NODES);
    k_mlp<<<MLP_BLOCKS, blk, 0, stream>>>(Ab, WT + 2 * 16384, b2a, WT + 3 * 16384, b2b, Xb, Srep2, N_NODES);
    k_bnfinalize<<<1, 128, 0, stream>>>(Srep2, g2, be2, SC2, N_NODES);

    // ---- pool (BN2+ReLU fused) + head ----
    k_pool<<<NGRAPH * 16, blk, 0, stream>>>(Xb, SC2, gstart, P);
    k_head<<<NGRAPH, 64, 0, stream>>>(P, gstart, Wl, bl, out);
}